// Round 12
// baseline (276.301 us; speedup 1.0000x reference)
//
#include <hip/hip_runtime.h>
#include <math.h>

#define TN 2048
#define DN 1024

typedef __attribute__((ext_vector_type(8))) _Float16 half8;
typedef __attribute__((ext_vector_type(4))) _Float16 half4v;
typedef __attribute__((ext_vector_type(4))) float f32x4;

__device__ __forceinline__ f32x4 mfma16(half8 a, half8 b, f32x4 c) {
  return __builtin_amdgcn_mfma_f32_16x16x32_f16(a, b, c, 0, 0, 0);
}

// lgkm-only barrier: vmem staging is synced per-wave (segment-private), never
// drained at barriers.
#define BAR_LDS()  asm volatile("s_waitcnt lgkmcnt(0)\ns_barrier" ::: "memory")

// Tile image layout (32 keys x 1024 feats, f16, 64KB):
//   elem_off(key,f) = (f>>4)*512 + perm(key>>2)*64 + (key&3)*16 + (f&15)
//   perm(kg) = (kg&1)*4 + (kg>>1)   (tr_read lane-group lg sees keys 8*lg+j)
// Wave w's PV tr-reads and staging writes live in elems [w*4096,(w+1)*4096)
// -> K staging syncs per-wave via counted vmcnt, no block barrier.
// QK A-frags are CONTIGUOUS 16B in this image -> loaded straight from L2
// (global), bypassing the LDS port entirely (LDS was ~85% busy in R11).
__device__ __forceinline__ int img_off(int key, int f) {
  const int kg = key >> 2;
  const int p  = ((kg & 1) << 2) | (kg >> 1);
  return (f >> 4) * 512 + p * 64 + (key & 3) * 16 + (f & 15);
}

// x fp32 [8][2048][1024] -> f16 tile images in ws: [b*64+tile][32768 elems]
__global__ __launch_bounds__(256) void convert_x(const float* __restrict__ x,
                                                 _Float16* __restrict__ w) {
  const long long gid = (long long)blockIdx.x * 256 + threadIdx.x;
  const long long e   = gid * 8;
  const int bt   = (int)(e >> 15);
  const int et   = (int)(e & 32767);
  const int f16b = et >> 9;
  const int p    = (et >> 6) & 7;
  const int row  = (et >> 4) & 3;
  const int col0 = et & 15;
  const int kg   = ((p & 3) << 1) | (p >> 2);    // inverse perm
  const int key  = kg * 4 + row;
  const size_t xoff = ((size_t)bt * 32 + key) * DN + f16b * 16 + col0;
  float4 u0 = *(const float4*)(x + xoff);
  float4 u1 = *(const float4*)(x + xoff + 4);
  half8 h = {(_Float16)u0.x, (_Float16)u0.y, (_Float16)u0.z, (_Float16)u0.w,
             (_Float16)u1.x, (_Float16)u1.y, (_Float16)u1.z, (_Float16)u1.w};
  *(half8*)(w + e) = h;
}

#define ISSUE4(T, O0, O1, O2, O3)                                             \
  asm volatile("ds_read_b64_tr_b16 %0, %4 offset:" O0 "\n\t"                  \
               "ds_read_b64_tr_b16 %1, %4 offset:" O1 "\n\t"                  \
               "ds_read_b64_tr_b16 %2, %4 offset:" O2 "\n\t"                  \
               "ds_read_b64_tr_b16 %3, %4 offset:" O3                         \
               : "=&v"(T[0]), "=&v"(T[1]), "=&v"(T[2]), "=&v"(T[3])           \
               : "v"(ab));

#define MFMA2(T, CT0, CT1)                                                    \
  {                                                                           \
    half8 bf0 = __builtin_shufflevector(T[0], T[1], 0, 1, 2, 3, 4, 5, 6, 7);  \
    half8 bf1 = __builtin_shufflevector(T[2], T[3], 0, 1, 2, 3, 4, 5, 6, 7);  \
    oacc[CT0] = mfma16(aP, bf0, oacc[CT0]);                                   \
    oacc[CT1] = mfma16(aP, bf1, oacc[CT1]);                                   \
  }

// One block = one (batch, 16-row q-tile). 1024 blocks, q16 descending.
// 8 waves, 8-way k-split QK with K A-frags from GLOBAL (L2) and 1-iter
// prefetch; LDS carries only staging + Sred roundtrip + PV tr-reads
// (200KB/iter vs R11's 264KB on an ~85%-busy LDS port).
// Sred rows padded to 44 elems (word-stride 22 -> all 16 lr rows hit
// distinct banks; fixes R11's 1.07e7 conflicts).
template <bool WS>
__global__ __launch_bounds__(512, 4)
void attn_gate(const float* __restrict__ x, const _Float16* __restrict__ wsx,
               const float* __restrict__ pla, const float* __restrict__ pls,
               float* __restrict__ out) {
  __shared__ _Float16 Kbuf[32768];       // single K tile image       64KB
  __shared__ _Float16 Sred[8][16][44];   // [slice][q-row][key, pad]  11KB
  __shared__ float l_s[16], gate_s[16];

  const int tid = threadIdx.x;
  const int w   = tid >> 6;       // wave 0..7 == kq (k-eighth, 128 feats)
  const int l   = tid & 63;
  const int lr  = l & 15;
  const int lg  = l >> 4;
  const int kq  = w;

  const int b   = blockIdx.x & 7;            // batch -> XCD
  const int q16 = 127 - (blockIdx.x >> 3);   // long blocks dispatched first
  const int qbase = q16 * 16;
  const int nkt   = (qbase + 14) / 32 + 1;   // 32-key tiles, strictly causal

  const float alpha = log1pf(expf(pla[0]));
  const float sigma = log1pf(expf(pls[0]));

  const float* xb = x + (size_t)b * TN * DN;
  float*       ob = out + (size_t)b * TN * DN;

  // K A-frag offsets (within a tile image): keys lr and 16+lr
  const int kg0 = lr >> 2;
  const int bk0 = ((((kg0 & 1) << 2) | (kg0 >> 1)) << 6) + (lr & 3) * 16 + (lg & 1) * 8;
  const int kg1 = 4 + (lr >> 2);
  const int bk1 = ((((kg1 & 1) << 2) | (kg1 >> 1)) << 6) + (lr & 3) * 16 + (lg & 1) * 8;

  const _Float16* wsb = WS ? (wsx + (size_t)b * 64 * 32768) : nullptr;

  auto STAGE = [&](int t) {   // WS: wave w writes ONLY its own segment
    if constexpr (WS) {
      const _Float16* tn = wsb + (size_t)t * 32768;
#pragma unroll
      for (int i = 0; i < 8; ++i)
        __builtin_amdgcn_global_load_lds(
            (const __attribute__((address_space(1))) void*)(tn + w * 4096 + i * 512 + l * 8),
            (__attribute__((address_space(3))) void*)(&Kbuf[w * 4096 + i * 512]), 16, 0, 0);
    } else {
      const int skey = tid >> 4, sc = tid & 15;
      const float* kp = xb + (size_t)(t * 32 + skey) * DN + sc * 4;
#pragma unroll
      for (int j = 0; j < 16; ++j) {
        const int f = sc * 4 + 64 * j;
        float4 v = *(const float4*)(kp + 64 * j);
        half4v h = {(_Float16)v.x, (_Float16)v.y, (_Float16)v.z, (_Float16)v.w};
        *(half4v*)&Kbuf[img_off(skey, f)] = h;
      }
    }
  };

  STAGE(0);

  // ---- Q fragments: row lr of this 16-row tile, k-eighth (16 VGPR) ----
  half8 qf[4];
  if constexpr (WS) {
    const _Float16* qtile = wsb + (size_t)(q16 >> 1) * 32768;
    const int qrow = (q16 & 1) * 16 + lr;
    const int g0   = qrow >> 2;
    const int qp   = (((g0 & 1) << 2) | (g0 >> 1)) * 64 + (qrow & 3) * 16 + (lg & 1) * 8;
#pragma unroll
    for (int s = 0; s < 4; ++s)
      qf[s] = *(const half8*)&qtile[(kq * 8 + s * 2 + (lg >> 1)) * 512 + qp];
  } else {
#pragma unroll
    for (int s = 0; s < 4; ++s) {
      const float* qp = xb + (size_t)(qbase + lr) * DN + kq * 128 + s * 32 + lg * 8;
      float4 a = ((const float4*)qp)[0];
      float4 c = ((const float4*)qp)[1];
      half8 h;
      h[0]=(_Float16)a.x; h[1]=(_Float16)a.y; h[2]=(_Float16)a.z; h[3]=(_Float16)a.w;
      h[4]=(_Float16)c.x; h[5]=(_Float16)c.y; h[6]=(_Float16)c.z; h[7]=(_Float16)c.w;
      qf[s] = h;
    }
  }

  // ---- K A-frag prefetch registers (tile 0) ----
  half8 af0[4], af1[4];
  if constexpr (WS) {
    const _Float16* t0p = wsb;   // tile 0
#pragma unroll
    for (int s = 0; s < 4; ++s) {
      const int base = (kq * 8 + s * 2 + (lg >> 1)) * 512;
      af0[s] = *(const half8*)&t0p[base + bk0];
      af1[s] = *(const half8*)&t0p[base + bk1];
    }
  }

  f32x4 oacc[8];
#pragma unroll
  for (int ct = 0; ct < 8; ++ct) oacc[ct] = f32x4{0.f, 0.f, 0.f, 0.f};
  float l0 = 0.0f;

  if constexpr (!WS) __syncthreads();   // fallback staging is cross-segment

  for (int t = 0; t < nkt; ++t) {
    // ---- QK^T (swapped): A = K keys (global-loaded frags), B = qf ----
    {
      f32x4 sA = f32x4{0.f,0.f,0.f,0.f};   // keys 0..15
      f32x4 sB = f32x4{0.f,0.f,0.f,0.f};   // keys 16..31
      if constexpr (WS) {
#pragma unroll
        for (int s = 0; s < 4; ++s) {
          sA = mfma16(af0[s], qf[s], sA);
          sB = mfma16(af1[s], qf[s], sB);
        }
      } else {
#pragma unroll
        for (int s = 0; s < 4; ++s) {
          const int base = (kq * 8 + s * 2 + (lg >> 1)) * 512;
          half8 bf0 = *(const half8*)&Kbuf[base + bk0];
          half8 bf1 = *(const half8*)&Kbuf[base + bk1];
          sA = mfma16(bf0, qf[s], sA);
          sB = mfma16(bf1, qf[s], sB);
        }
      }
      half4v hA = {(_Float16)sA[0], (_Float16)sA[1], (_Float16)sA[2], (_Float16)sA[3]};
      half4v hB = {(_Float16)sB[0], (_Float16)sB[1], (_Float16)sB[2], (_Float16)sB[3]};
      *(half4v*)&Sred[kq][lr][lg * 4]      = hA;   // keys lg*4..+3
      *(half4v*)&Sred[kq][lr][16 + lg * 4] = hB;   // keys 16+lg*4..+3
    }

    // ---- prefetch K A-frags for tile t+1 (issued BEFORE stage(t+1):
    //      FIFO vmcnt lets both sides use counted waits) ----
    if constexpr (WS) {
      if (t + 1 < nkt) {
        const _Float16* tn = wsb + (size_t)(t + 1) * 32768;
#pragma unroll
        for (int s = 0; s < 4; ++s) {
          const int base = (kq * 8 + s * 2 + (lg >> 1)) * 512;
          af0[s] = *(const half8*)&tn[base + bk0];
          af1[s] = *(const half8*)&tn[base + bk1];
        }
      }
    }
    BAR_LDS();   // (A) Sred ready

    // ---- fused exp + PV ----
    {
      // A-frag inputs: 8 slices of (row lr, keys lg*8..+7)
      half8 r0 = *(const half8*)&Sred[0][lr][lg * 8];
      half8 r1 = *(const half8*)&Sred[1][lr][lg * 8];
      half8 r2 = *(const half8*)&Sred[2][lr][lg * 8];
      half8 r3 = *(const half8*)&Sred[3][lr][lg * 8];
      half8 r4 = *(const half8*)&Sred[4][lr][lg * 8];
      half8 r5 = *(const half8*)&Sred[5][lr][lg * 8];
      half8 r6 = *(const half8*)&Sred[6][lr][lg * 8];
      half8 r7 = *(const half8*)&Sred[7][lr][lg * 8];
      half8 sum = ((r0 + r1) + (r2 + r3)) + ((r4 + r5) + (r6 + r7));

      const bool mt = (t == nkt - 1);
      const int  gb = 32 * t + lg * 8;     // this lane's global key base
      half8 aP;
#pragma unroll
      for (int j = 0; j < 8; ++j) {
        float p = __expf((float)sum[j] * 0.03125f);
        if (mt && (gb + j >= qbase + lr)) p = 0.0f;   // strictly-causal
        l0 += p;
        aP[j] = (_Float16)p;
      }

      const uint32_t ab = (uint32_t)(uintptr_t)(void*)&Kbuf[w * 4096 + l * 4];
      // entry fences: compiler LDS drained; stage(t) landed (af(t+1), the 8
      // newest vmem ops, may stay in flight)
      asm volatile("s_waitcnt lgkmcnt(0)" ::: "memory");
      if constexpr (WS) {
        if (t + 1 < nkt) asm volatile("s_waitcnt vmcnt(8)" ::: "memory");
        else             asm volatile("s_waitcnt vmcnt(0)" ::: "memory");
      }
      __builtin_amdgcn_sched_barrier(0);
      half4v t0[4], t1[4];
      ISSUE4(t0, "0", "512", "1024", "1536");
      ISSUE4(t1, "2048", "2560", "3072", "3584");
      asm volatile("s_waitcnt lgkmcnt(4)" ::: "memory");
      __builtin_amdgcn_sched_barrier(0);
      MFMA2(t0, 0, 1);
      ISSUE4(t0, "4096", "4608", "5120", "5632");
      asm volatile("s_waitcnt lgkmcnt(4)" ::: "memory");
      __builtin_amdgcn_sched_barrier(0);
      MFMA2(t1, 2, 3);
      ISSUE4(t1, "6144", "6656", "7168", "7680");
      asm volatile("s_waitcnt lgkmcnt(4)" ::: "memory");
      __builtin_amdgcn_sched_barrier(0);
      MFMA2(t0, 4, 5);
      asm volatile("s_waitcnt lgkmcnt(0)" ::: "memory");   // all tr reads done
      __builtin_amdgcn_sched_barrier(0);
      MFMA2(t1, 6, 7);
    }

    // ---- restage own segment (tr reads drained above); in flight across
    //      BAR + next iteration until the pre-PV vmcnt ----
    if (t + 1 < nkt) {
      if constexpr (!WS) __syncthreads();   // fallback: cross-segment writes
      STAGE(t + 1);
    }
    BAR_LDS();   // (B) Sred free for next QK's writes
  }

  // ---- l reduce (replicated across waves; reduce over lg key-groups) ----
  {
    float lt = l0 + __shfl_xor(l0, 16);
    lt += __shfl_xor(lt, 32);
    if (w == 0 && lg == 0) l_s[lr] = lt;
  }

  // ---- epilogue: per-row <x,O>, |x|^2, |O|^2 (per-wave 128-feat slice) ----
  {
    float* ered = (float*)&Sred[0][0][0];   // reuse 2KB
#pragma unroll
    for (int j = 0; j < 4; ++j) {
      const int row = lg * 4 + j;
      const float* xr = xb + (size_t)(qbase + row) * DN + w * 128 + lr;
      float a1 = 0.f, a2 = 0.f, a3 = 0.f;
#pragma unroll
      for (int ct = 0; ct < 8; ++ct) {
        const float xv = xr[ct * 16];
        const float ov = oacc[ct][j];
        a1 += xv * ov; a2 += xv * xv; a3 += ov * ov;
      }
#pragma unroll
      for (int d = 1; d < 16; d <<= 1) {
        a1 += __shfl_xor(a1, d);
        a2 += __shfl_xor(a2, d);
        a3 += __shfl_xor(a3, d);
      }
      if (lr == 0) {
        float* e = ered + (row * 8 + w) * 4;
        e[0] = a1; e[1] = a2; e[2] = a3;
      }
    }
  }
  __syncthreads();
  if (tid < 16) {
    const float* ered = (const float*)&Sred[0][0][0];
    float SxO = 0.f, Sxx = 0.f, SOO = 0.f;
#pragma unroll
    for (int wv = 0; wv < 8; ++wv) {
      const float* e = ered + (tid * 8 + wv) * 4;
      SxO += e[0]; Sxx += e[1]; SOO += e[2];
    }
    const float lden = l_s[tid];
    float cosv = 0.0f;
    if (lden > 0.0f) {
      const float nx = fmaxf(sqrtf(Sxx), 1e-12f);
      const float nc = fmaxf(sqrtf(SOO) / lden, 1e-12f);
      cosv = (SxO / lden) / (nx * nc);
    }
    float nov = fminf(fmaxf(1.0f - cosv, 0.0f), 2.0f) * 0.5f;
    gate_s[tid] = 1.0f + alpha * tanhf(sigma * nov);
  }
  __syncthreads();
  {
#pragma unroll
    for (int j = 0; j < 4; ++j) {
      const int row = lg * 4 + j;
      const float g = gate_s[row];
      const float* xr = xb + (size_t)(qbase + row) * DN + w * 128 + lr;
      float* orow     = ob + (size_t)(qbase + row) * DN + w * 128 + lr;
#pragma unroll
      for (int ct = 0; ct < 8; ++ct) {
        const float z = xr[ct * 16] * g;
        const float u = 0.7978845608028654f * (z + 0.044715f * z * z * z);
        orow[ct * 16] = 0.5f * z * (1.0f + tanhf(u));
      }
    }
  }
}

extern "C" void kernel_launch(void* const* d_in, const int* in_sizes, int n_in,
                              void* d_out, int out_size, void* d_ws, size_t ws_size,
                              hipStream_t stream) {
  const float* x  = (const float*)d_in[0];
  const float* la = (const float*)d_in[1];
  const float* ls = (const float*)d_in[2];
  float* out = (float*)d_out;
  const size_t need = (size_t)8 * 64 * 32768 * 2;   // 32 MB f16 tile images
  if (ws_size >= need) {
    convert_x<<<dim3(8192), dim3(256), 0, stream>>>(x, (_Float16*)d_ws);
    attn_gate<true><<<dim3(1024), dim3(512), 0, stream>>>(
        x, (const _Float16*)d_ws, la, ls, out);
  } else {
    attn_gate<false><<<dim3(1024), dim3(512), 0, stream>>>(
        x, (const _Float16*)nullptr, la, ls, out);
  }
}

// Round 13
// 194.270 us; speedup vs baseline: 1.4223x; 1.4223x over previous
//
#include <hip/hip_runtime.h>
#include <math.h>

#define TN 2048
#define DN 1024

typedef __attribute__((ext_vector_type(8))) _Float16 half8;
typedef __attribute__((ext_vector_type(4))) _Float16 half4v;
typedef __attribute__((ext_vector_type(4))) float f32x4;

__device__ __forceinline__ f32x4 mfma16(half8 a, half8 b, f32x4 c) {
  return __builtin_amdgcn_mfma_f32_16x16x32_f16(a, b, c, 0, 0, 0);
}

// lgkm-only barrier: vmem staging is synced per-wave (segment-private), never
// drained at barriers.
#define BAR_LDS()  asm volatile("s_waitcnt lgkmcnt(0)\ns_barrier" ::: "memory")
#define WAITVM0()  asm volatile("s_waitcnt vmcnt(0)" ::: "memory")

// Tile image layout (32 keys x 1024 feats, f16, 64KB):
//   elem_off(key,f) = (f>>4)*512 + perm(key>>2)*64 + (key&3)*16 + (f&15)
//   perm(kg) = (kg&1)*4 + (kg>>1)   (tr_read lane-group lg sees keys 8*lg+j)
// Wave w's QK reads, PV tr-reads AND staging writes all live in elems
// [w*4096,(w+1)*4096) -> K staging syncs per-wave via vmcnt, no barrier.
__device__ __forceinline__ int img_off(int key, int f) {
  const int kg = key >> 2;
  const int p  = ((kg & 1) << 2) | (kg >> 1);
  return (f >> 4) * 512 + p * 64 + (key & 3) * 16 + (f & 15);
}

// x fp32 [8][2048][1024] -> f16 tile images in ws: [b*64+tile][32768 elems]
__global__ __launch_bounds__(256) void convert_x(const float* __restrict__ x,
                                                 _Float16* __restrict__ w) {
  const long long gid = (long long)blockIdx.x * 256 + threadIdx.x;
  const long long e   = gid * 8;
  const int bt   = (int)(e >> 15);
  const int et   = (int)(e & 32767);
  const int f16b = et >> 9;
  const int p    = (et >> 6) & 7;
  const int row  = (et >> 4) & 3;
  const int col0 = et & 15;
  const int kg   = ((p & 3) << 1) | (p >> 2);    // inverse perm
  const int key  = kg * 4 + row;
  const size_t xoff = ((size_t)bt * 32 + key) * DN + f16b * 16 + col0;
  float4 u0 = *(const float4*)(x + xoff);
  float4 u1 = *(const float4*)(x + xoff + 4);
  half8 h = {(_Float16)u0.x, (_Float16)u0.y, (_Float16)u0.z, (_Float16)u0.w,
             (_Float16)u1.x, (_Float16)u1.y, (_Float16)u1.z, (_Float16)u1.w};
  *(half8*)(w + e) = h;
}

#define ISSUE4(T, O0, O1, O2, O3)                                             \
  asm volatile("ds_read_b64_tr_b16 %0, %4 offset:" O0 "\n\t"                  \
               "ds_read_b64_tr_b16 %1, %4 offset:" O1 "\n\t"                  \
               "ds_read_b64_tr_b16 %2, %4 offset:" O2 "\n\t"                  \
               "ds_read_b64_tr_b16 %3, %4 offset:" O3                         \
               : "=&v"(T[0]), "=&v"(T[1]), "=&v"(T[2]), "=&v"(T[3])           \
               : "v"(ab));

#define MFMA2(T, CT0, CT1)                                                    \
  {                                                                           \
    half8 bf0 = __builtin_shufflevector(T[0], T[1], 0, 1, 2, 3, 4, 5, 6, 7);  \
    half8 bf1 = __builtin_shufflevector(T[2], T[3], 0, 1, 2, 3, 4, 5, 6, 7);  \
    oacc[CT0] = mfma16(aP, bf0, oacc[CT0]);                                   \
    oacc[CT1] = mfma16(aP, bf1, oacc[CT1]);                                   \
  }

// One block = one (batch, 16-row q-tile). 1024 blocks, q16 descending.
// 8 waves, 8-way k-split QK (swapped mfma(K,Q)). No-max softmax.
// Single 64KB Kbuf, wave-private segment staging (vmcnt-synced).
// R13 = R11 (2 blocks/CU, VGPR 52+32, no global-A-frag regs) +
//       R12's Sred row stride 44 (word-stride 22: conflicts 1.07e7 -> 1e5).
template <bool WS>
__global__ __launch_bounds__(512, 4)
void attn_gate(const float* __restrict__ x, const _Float16* __restrict__ wsx,
               const float* __restrict__ pla, const float* __restrict__ pls,
               float* __restrict__ out) {
  __shared__ _Float16 Kbuf[32768];       // single K tile image       64KB
  __shared__ _Float16 Sred[8][16][44];   // [slice][q-row][key, pad]  11KB
  __shared__ float l_s[16], gate_s[16];

  const int tid = threadIdx.x;
  const int w   = tid >> 6;       // wave 0..7 == kq (k-eighth, 128 feats)
  const int l   = tid & 63;
  const int lr  = l & 15;
  const int lg  = l >> 4;
  const int kq  = w;

  const int b   = blockIdx.x & 7;            // batch -> XCD
  const int q16 = 127 - (blockIdx.x >> 3);   // long blocks dispatched first
  const int qbase = q16 * 16;
  const int nkt   = (qbase + 14) / 32 + 1;   // 32-key tiles, strictly causal

  const float alpha = log1pf(expf(pla[0]));
  const float sigma = log1pf(expf(pls[0]));

  const float* xb = x + (size_t)b * TN * DN;
  float*       ob = out + (size_t)b * TN * DN;

  // QK A-frag offsets (K as A-operand): keys lr and 16+lr
  const int kg0 = lr >> 2;
  const int bk0 = ((((kg0 & 1) << 2) | (kg0 >> 1)) << 6) + (lr & 3) * 16 + (lg & 1) * 8;
  const int kg1 = 4 + (lr >> 2);
  const int bk1 = ((((kg1 & 1) << 2) | (kg1 >> 1)) << 6) + (lr & 3) * 16 + (lg & 1) * 8;

  auto STAGE = [&](int t) {   // WS: wave w writes ONLY its own segment
    if constexpr (WS) {
      const _Float16* tn = wsx + (size_t)(b * 64 + t) * 32768;
#pragma unroll
      for (int i = 0; i < 8; ++i)
        __builtin_amdgcn_global_load_lds(
            (const __attribute__((address_space(1))) void*)(tn + w * 4096 + i * 512 + l * 8),
            (__attribute__((address_space(3))) void*)(&Kbuf[w * 4096 + i * 512]), 16, 0, 0);
    } else {
      const int skey = tid >> 4, sc = tid & 15;
      const float* kp = xb + (size_t)(t * 32 + skey) * DN + sc * 4;
#pragma unroll
      for (int j = 0; j < 16; ++j) {
        const int f = sc * 4 + 64 * j;
        float4 v = *(const float4*)(kp + 64 * j);
        half4v h = {(_Float16)v.x, (_Float16)v.y, (_Float16)v.z, (_Float16)v.w};
        *(half4v*)&Kbuf[img_off(skey, f)] = h;
      }
    }
  };

  STAGE(0);

  // ---- Q fragments: row lr of this 16-row tile, k-eighth (16 VGPR) ----
  half8 qf[4];
  if constexpr (WS) {
    const _Float16* qtile = wsx + (size_t)(b * 64 + (q16 >> 1)) * 32768;
    const int qrow = (q16 & 1) * 16 + lr;
    const int g0   = qrow >> 2;
    const int qp   = (((g0 & 1) << 2) | (g0 >> 1)) * 64 + (qrow & 3) * 16 + (lg & 1) * 8;
#pragma unroll
    for (int s = 0; s < 4; ++s)
      qf[s] = *(const half8*)&qtile[(kq * 8 + s * 2 + (lg >> 1)) * 512 + qp];
  } else {
#pragma unroll
    for (int s = 0; s < 4; ++s) {
      const float* qp = xb + (size_t)(qbase + lr) * DN + kq * 128 + s * 32 + lg * 8;
      float4 a = ((const float4*)qp)[0];
      float4 c = ((const float4*)qp)[1];
      half8 h;
      h[0]=(_Float16)a.x; h[1]=(_Float16)a.y; h[2]=(_Float16)a.z; h[3]=(_Float16)a.w;
      h[4]=(_Float16)c.x; h[5]=(_Float16)c.y; h[6]=(_Float16)c.z; h[7]=(_Float16)c.w;
      qf[s] = h;
    }
  }

  f32x4 oacc[8];
#pragma unroll
  for (int ct = 0; ct < 8; ++ct) oacc[ct] = f32x4{0.f, 0.f, 0.f, 0.f};
  float l0 = 0.0f;

  if constexpr (!WS) __syncthreads();   // fallback staging is cross-segment

  for (int t = 0; t < nkt; ++t) {
    if constexpr (WS) WAITVM0();   // own-segment stage(t) landed

    // ---- QK^T (swapped): D[key_local][q-row]; lane -> 4 consecutive keys ----
    {
      f32x4 sA = f32x4{0.f,0.f,0.f,0.f};   // keys 0..15
      f32x4 sB = f32x4{0.f,0.f,0.f,0.f};   // keys 16..31
#pragma unroll
      for (int s = 0; s < 4; ++s) {
        const int base = (kq * 8 + s * 2 + (lg >> 1)) * 512;
        half8 bf0 = *(const half8*)&Kbuf[base + bk0];
        half8 bf1 = *(const half8*)&Kbuf[base + bk1];
        sA = mfma16(bf0, qf[s], sA);
        sB = mfma16(bf1, qf[s], sB);
      }
      half4v hA = {(_Float16)sA[0], (_Float16)sA[1], (_Float16)sA[2], (_Float16)sA[3]};
      half4v hB = {(_Float16)sB[0], (_Float16)sB[1], (_Float16)sB[2], (_Float16)sB[3]};
      *(half4v*)&Sred[kq][lr][lg * 4]      = hA;   // keys lg*4..+3
      *(half4v*)&Sred[kq][lr][16 + lg * 4] = hB;   // keys 16+lg*4..+3
    }
    BAR_LDS();   // (A) Sred ready

    // ---- fused exp + PV ----
    {
      // A-frag inputs: 8 slices of (row lr, keys lg*8..+7)
      half8 r0 = *(const half8*)&Sred[0][lr][lg * 8];
      half8 r1 = *(const half8*)&Sred[1][lr][lg * 8];
      half8 r2 = *(const half8*)&Sred[2][lr][lg * 8];
      half8 r3 = *(const half8*)&Sred[3][lr][lg * 8];
      half8 r4 = *(const half8*)&Sred[4][lr][lg * 8];
      half8 r5 = *(const half8*)&Sred[5][lr][lg * 8];
      half8 r6 = *(const half8*)&Sred[6][lr][lg * 8];
      half8 r7 = *(const half8*)&Sred[7][lr][lg * 8];
      half8 sum = ((r0 + r1) + (r2 + r3)) + ((r4 + r5) + (r6 + r7));

      const bool mt = (t == nkt - 1);
      const int  gb = 32 * t + lg * 8;     // this lane's global key base
      half8 aP;
#pragma unroll
      for (int j = 0; j < 8; ++j) {
        float p = __expf((float)sum[j] * 0.03125f);
        if (mt && (gb + j >= qbase + lr)) p = 0.0f;   // strictly-causal
        l0 += p;
        aP[j] = (_Float16)p;
      }

      const uint32_t ab = (uint32_t)(uintptr_t)(void*)&Kbuf[w * 4096 + l * 4];
      asm volatile("s_waitcnt lgkmcnt(0)" ::: "memory");
      __builtin_amdgcn_sched_barrier(0);
      half4v t0[4], t1[4];
      ISSUE4(t0, "0", "512", "1024", "1536");
      ISSUE4(t1, "2048", "2560", "3072", "3584");
      asm volatile("s_waitcnt lgkmcnt(4)" ::: "memory");
      __builtin_amdgcn_sched_barrier(0);
      MFMA2(t0, 0, 1);
      ISSUE4(t0, "4096", "4608", "5120", "5632");
      asm volatile("s_waitcnt lgkmcnt(4)" ::: "memory");
      __builtin_amdgcn_sched_barrier(0);
      MFMA2(t1, 2, 3);
      ISSUE4(t1, "6144", "6656", "7168", "7680");
      asm volatile("s_waitcnt lgkmcnt(4)" ::: "memory");
      __builtin_amdgcn_sched_barrier(0);
      MFMA2(t0, 4, 5);
      asm volatile("s_waitcnt lgkmcnt(0)" ::: "memory");   // all tr reads done
      __builtin_amdgcn_sched_barrier(0);
      MFMA2(t1, 6, 7);
    }

    // ---- restage own segment (tr reads drained above); in flight across
    //      BAR + next QK's WAITVM0 ----
    if (t + 1 < nkt) {
      if constexpr (!WS) __syncthreads();   // fallback: cross-segment writes
      STAGE(t + 1);
    }
    BAR_LDS();   // (B) Sred free for next QK's writes
  }

  // ---- l reduce (replicated across waves; reduce over lg key-groups) ----
  {
    float lt = l0 + __shfl_xor(l0, 16);
    lt += __shfl_xor(lt, 32);
    if (w == 0 && lg == 0) l_s[lr] = lt;
  }

  // ---- epilogue: per-row <x,O>, |x|^2, |O|^2 (per-wave 128-feat slice) ----
  {
    float* ered = (float*)&Sred[0][0][0];   // reuse 2KB
#pragma unroll
    for (int j = 0; j < 4; ++j) {
      const int row = lg * 4 + j;
      const float* xr = xb + (size_t)(qbase + row) * DN + w * 128 + lr;
      float a1 = 0.f, a2 = 0.f, a3 = 0.f;
#pragma unroll
      for (int ct = 0; ct < 8; ++ct) {
        const float xv = xr[ct * 16];
        const float ov = oacc[ct][j];
        a1 += xv * ov; a2 += xv * xv; a3 += ov * ov;
      }
#pragma unroll
      for (int d = 1; d < 16; d <<= 1) {
        a1 += __shfl_xor(a1, d);
        a2 += __shfl_xor(a2, d);
        a3 += __shfl_xor(a3, d);
      }
      if (lr == 0) {
        float* e = ered + (row * 8 + w) * 4;
        e[0] = a1; e[1] = a2; e[2] = a3;
      }
    }
  }
  __syncthreads();
  if (tid < 16) {
    const float* ered = (const float*)&Sred[0][0][0];
    float SxO = 0.f, Sxx = 0.f, SOO = 0.f;
#pragma unroll
    for (int wv = 0; wv < 8; ++wv) {
      const float* e = ered + (tid * 8 + wv) * 4;
      SxO += e[0]; Sxx += e[1]; SOO += e[2];
    }
    const float lden = l_s[tid];
    float cosv = 0.0f;
    if (lden > 0.0f) {
      const float nx = fmaxf(sqrtf(Sxx), 1e-12f);
      const float nc = fmaxf(sqrtf(SOO) / lden, 1e-12f);
      cosv = (SxO / lden) / (nx * nc);
    }
    float nov = fminf(fmaxf(1.0f - cosv, 0.0f), 2.0f) * 0.5f;
    gate_s[tid] = 1.0f + alpha * tanhf(sigma * nov);
  }
  __syncthreads();
  {
#pragma unroll
    for (int j = 0; j < 4; ++j) {
      const int row = lg * 4 + j;
      const float g = gate_s[row];
      const float* xr = xb + (size_t)(qbase + row) * DN + w * 128 + lr;
      float* orow     = ob + (size_t)(qbase + row) * DN + w * 128 + lr;
#pragma unroll
      for (int ct = 0; ct < 8; ++ct) {
        const float z = xr[ct * 16] * g;
        const float u = 0.7978845608028654f * (z + 0.044715f * z * z * z);
        orow[ct * 16] = 0.5f * z * (1.0f + tanhf(u));
      }
    }
  }
}

extern "C" void kernel_launch(void* const* d_in, const int* in_sizes, int n_in,
                              void* d_out, int out_size, void* d_ws, size_t ws_size,
                              hipStream_t stream) {
  const float* x  = (const float*)d_in[0];
  const float* la = (const float*)d_in[1];
  const float* ls = (const float*)d_in[2];
  float* out = (float*)d_out;
  const size_t need = (size_t)8 * 64 * 32768 * 2;   // 32 MB f16 tile images
  if (ws_size >= need) {
    convert_x<<<dim3(8192), dim3(256), 0, stream>>>(x, (_Float16*)d_ws);
    attn_gate<true><<<dim3(1024), dim3(512), 0, stream>>>(
        x, (const _Float16*)d_ws, la, ls, out);
  } else {
    attn_gate<false><<<dim3(1024), dim3(512), 0, stream>>>(
        x, (const _Float16*)nullptr, la, ls, out);
  }
}